// Round 9
// baseline (36.116 us; speedup 1.0000x reference)
//
#include <hip/hip_runtime.h>

// skipgram negative-sampling loss, MI355X — round 9.
// Model under test: R8 saturated the async-gather queue; time now tracks
// 128B-line service rate (~184MB of line-touches). Halve lines: v-table
// converted to bf16 (stream, ~12.5us), gathers fetch 4 bf16 rows (256B) per
// global_load_lds size=16 instruction. One wave per row-PAIR, all 20 negs of
// both rows = 10 async instructions, 10KB LDS/wave, 14 waves/CU (unchanged
// saturation). Accuracy: bf16 round-half-up rel err <=2^-9 -> loss err ~2e-4
// vs 2.8e-2 threshold.

constexpr int DIM  = 128;
constexpr int KNEG = 20;

__device__ __forceinline__ float log_sigmoid(float x) {
    return fminf(x, 0.0f) - log1pf(__expf(-fabsf(x)));
}

__device__ __forceinline__ float b2f(unsigned short h) {
    return __uint_as_float((unsigned int)h << 16);
}

typedef __attribute__((address_space(3))) unsigned int       lds_uint;
typedef const __attribute__((address_space(1))) unsigned int glob_uint;

// ---------- phase 0: v_emb f32 -> bf16 (round-half-up) ----------
__global__ __launch_bounds__(256) void convert_kernel(
    const float* __restrict__ src, unsigned short* __restrict__ dst, int n4)
{
    int i = blockIdx.x * blockDim.x + threadIdx.x;
    const int stride = gridDim.x * blockDim.x;
    const float4* s4 = reinterpret_cast<const float4*>(src);
    ushort4* d4 = reinterpret_cast<ushort4*>(dst);
    for (; i < n4; i += stride) {
        float4 v = s4[i];
        ushort4 o;
        o.x = (unsigned short)((__float_as_uint(v.x) + 0x8000u) >> 16);
        o.y = (unsigned short)((__float_as_uint(v.y) + 0x8000u) >> 16);
        o.z = (unsigned short)((__float_as_uint(v.z) + 0x8000u) >> 16);
        o.w = (unsigned short)((__float_as_uint(v.w) + 0x8000u) >> 16);
        d4[i] = o;
    }
}

// ---------- stage 1: one WAVE = one row-pair, bf16 async gathers ----------
// Chunk j (1KB LDS): rows {nA[2j], nA[2j+1], nB[2j], nB[2j+1]}, 256B each.
// Writer: lane l (q=l>>4 picks row, s=l&15) puts 16B at chunk+l*16.
// Reader: lane (half=l>>5, l32=l&31) takes dims [4*l32,4*l32+4) of row
// (half*2+t) at chunk byte (half*2+t)*256 + l32*8.
__global__ __launch_bounds__(128) void skipgram_stage1(
    const float* __restrict__ u_emb, const unsigned short* __restrict__ v_half,
    const int* __restrict__ u_pos, const int* __restrict__ v_pos,
    const int* __restrict__ v_neg, float* __restrict__ pair_loss, int npairs)
{
    __shared__ unsigned short lds_negs[2][10 * 512];   // 10KB per wave

    const int lane = threadIdx.x & 63;
    const int w    = threadIdx.x >> 6;                 // wave slot 0/1
    const int pair = __builtin_amdgcn_readfirstlane(blockIdx.x * 2 + w);
    if (pair >= npairs) return;
    const int rowA = pair * 2, rowB = rowA + 1;
    const int half = lane >> 5, l32 = lane & 31;
    const int q    = lane >> 4, s   = lane & 15;

    // ---- uniform scalar index loads ----
    const int upA = u_pos[rowA], upB = u_pos[rowB];
    const int vpA = v_pos[rowA], vpB = v_pos[rowB];
    int nA[KNEG], nB[KNEG];
    const int4* pa = reinterpret_cast<const int4*>(v_neg + (size_t)rowA * KNEG);
    const int4* pb = reinterpret_cast<const int4*>(v_neg + (size_t)rowB * KNEG);
    #pragma unroll
    for (int j = 0; j < 5; ++j) {
        int4 a = pa[j], b = pb[j];
        nA[4*j+0]=a.x; nA[4*j+1]=a.y; nA[4*j+2]=a.z; nA[4*j+3]=a.w;
        nB[4*j+0]=b.x; nB[4*j+1]=b.y; nB[4*j+2]=b.z; nB[4*j+3]=b.w;
    }

    // ---- 10 async gathers, 4 bf16 rows per instruction, all in flight ----
    unsigned short* lb = &lds_negs[w][0];
    #pragma unroll
    for (int j = 0; j < 10; ++j) {
        const int r0 = nA[2*j], r1 = nA[2*j+1], r2 = nB[2*j], r3 = nB[2*j+1];
        const int r  = (q == 0) ? r0 : (q == 1) ? r1 : (q == 2) ? r2 : r3;
        const unsigned short* g = v_half + (size_t)r * DIM + s * 8;   // 16B chunk
        __builtin_amdgcn_global_load_lds((glob_uint*)g,
                                         (lds_uint*)(lb + j * 512), 16, 0, 0);
    }

    // ---- register loads: u row f32, v_pos row bf16 ----
    const float* urow = u_emb + (size_t)(half ? upB : upA) * DIM;
    const float4 uu = *reinterpret_cast<const float4*>(urow + l32 * 4);
    const unsigned short* vrow = v_half + (size_t)(half ? vpB : vpA) * DIM;
    const ushort4 vh = *reinterpret_cast<const ushort4*>(vrow + l32 * 4);

    asm volatile("s_waitcnt vmcnt(0)" ::: "memory");
    __builtin_amdgcn_sched_barrier(0);

    float pos = fmaf(uu.x, b2f(vh.x), fmaf(uu.y, b2f(vh.y),
                fmaf(uu.z, b2f(vh.z), uu.w * b2f(vh.w))));

    float ax = 0.0f, ay = 0.0f, az = 0.0f, aw = 0.0f;
    #pragma unroll
    for (int j = 0; j < 10; ++j) {
        #pragma unroll
        for (int t = 0; t < 2; ++t) {
            const ushort4 h = *reinterpret_cast<const ushort4*>(
                &lds_negs[w][j * 512 + half * 256 + t * 128 + l32 * 4]);
            ax += b2f(h.x); ay += b2f(h.y); az += b2f(h.z); aw += b2f(h.w);
        }
    }
    float neg = fmaf(uu.x, ax, fmaf(uu.y, ay, fmaf(uu.z, az, uu.w * aw)));

    // ---- butterfly within each 32-lane half; lane0=rowA, lane32=rowB ----
    #pragma unroll
    for (int off = 16; off; off >>= 1) {
        pos += __shfl_xor(pos, off);
        neg += __shfl_xor(neg, off);
    }

    float bl = 0.0f;
    if (l32 == 0) bl = log_sigmoid(pos) + log_sigmoid(-neg);
    bl += __shfl_xor(bl, 32);                  // lane0: lossA + lossB
    if (lane == 0) pair_loss[pair] = bl;
}

// ---------- stage 2: reduce 8192 per-pair losses, plain store ----------
__global__ __launch_bounds__(1024) void skipgram_stage2(
    const float* __restrict__ pair_loss, float* __restrict__ out,
    int n, float neg_inv_b)
{
    float acc = 0.0f;
    for (int i = threadIdx.x; i < n; i += 1024) acc += pair_loss[i];

    #pragma unroll
    for (int off = 32; off; off >>= 1) acc += __shfl_xor(acc, off);

    __shared__ float wsum[16];
    const int lane = threadIdx.x & 63;
    const int w    = threadIdx.x >> 6;
    if (lane == 0) wsum[w] = acc;
    __syncthreads();
    if (threadIdx.x == 0) {
        float s = 0.0f;
        #pragma unroll
        for (int i = 0; i < 16; ++i) s += wsum[i];
        out[0] = s * neg_inv_b;
    }
}

// ---------- fallback: single-kernel f32 if ws too small ----------
__global__ __launch_bounds__(256) void skipgram_f32_kernel(
    const float* __restrict__ u_emb, const float* __restrict__ v_emb,
    const int* __restrict__ u_pos, const int* __restrict__ v_pos,
    const int* __restrict__ v_neg, float* __restrict__ out,
    int B, float neg_inv_b)
{
    const int lane  = threadIdx.x & 63;
    const int wslot = threadIdx.x >> 6;
    const int row   = blockIdx.x * 4 + wslot;

    float contrib = 0.0f;
    if (row < B) {
        const int up = u_pos[row];
        const int vp = v_pos[row];
        int idx[KNEG];
        #pragma unroll
        for (int k = 0; k < KNEG; ++k) idx[k] = v_neg[row * KNEG + k];
        const float2 uu = reinterpret_cast<const float2*>(u_emb + (size_t)up * DIM)[lane];
        const float2 vv = reinterpret_cast<const float2*>(v_emb + (size_t)vp * DIM)[lane];
        float pos = fmaf(uu.x, vv.x, uu.y * vv.y);
        float ax = 0.0f, ay = 0.0f;
        #pragma unroll
        for (int k = 0; k < KNEG; ++k) {
            float2 nv = reinterpret_cast<const float2*>(v_emb + (size_t)idx[k] * DIM)[lane];
            ax += nv.x; ay += nv.y;
        }
        float neg = fmaf(uu.x, ax, uu.y * ay);
        #pragma unroll
        for (int off = 32; off; off >>= 1) {
            pos += __shfl_xor(pos, off);
            neg += __shfl_xor(neg, off);
        }
        contrib = (lane == 0) ? (log_sigmoid(pos) + log_sigmoid(-neg)) : 0.0f;
    }

    __shared__ float wsum[4];
    if (lane == 0) wsum[wslot] = contrib;
    __syncthreads();
    if (threadIdx.x == 0) {
        float s = 0.0f;
        #pragma unroll
        for (int w = 0; w < 4; ++w) s += wsum[w];
        atomicAdd(out, s * neg_inv_b);
    }
}

extern "C" void kernel_launch(void* const* d_in, const int* in_sizes, int n_in,
                              void* d_out, int out_size, void* d_ws, size_t ws_size,
                              hipStream_t stream) {
    const float* u_emb = (const float*)d_in[0];
    const float* v_emb = (const float*)d_in[1];
    const int*   u_pos = (const int*)d_in[2];
    const int*   v_pos = (const int*)d_in[3];
    const int*   v_neg = (const int*)d_in[4];
    float* out = (float*)d_out;

    const int B      = in_sizes[2];            // 16384
    const int vElems = in_sizes[1];            // 12.8M
    const int pairs  = B / 2;                  // 8192

    const size_t tab_bytes = (size_t)vElems * sizeof(unsigned short);
    const size_t needed    = tab_bytes + (size_t)pairs * sizeof(float);

    if (ws_size >= needed && (B % 2) == 0 && (vElems % 4) == 0) {
        unsigned short* v_half = (unsigned short*)d_ws;
        float* pair_loss = (float*)((char*)d_ws + tab_bytes);

        convert_kernel<<<2048, 256, 0, stream>>>(v_emb, v_half, vElems / 4);

        skipgram_stage1<<<(pairs + 1) / 2, 128, 0, stream>>>(
            u_emb, v_half, u_pos, v_pos, v_neg, pair_loss, pairs);

        skipgram_stage2<<<1, 1024, 0, stream>>>(
            pair_loss, out, pairs, -1.0f / (float)B);
    } else {
        hipMemsetAsync(out, 0, sizeof(float), stream);
        const int blocks = (B + 3) / 4;
        skipgram_f32_kernel<<<blocks, 256, 0, stream>>>(
            u_emb, v_emb, u_pos, v_pos, v_neg, out, B, -1.0f / (float)B);
    }
}